// Round 8
// baseline (131.420 us; speedup 1.0000x reference)
//
#include <hip/hip_runtime.h>
#include <hip/hip_bf16.h>
#include <math.h>

typedef unsigned short u16;
typedef _Float16 f16x8 __attribute__((ext_vector_type(8)));
typedef float    f32x16 __attribute__((ext_vector_type(16)));
typedef u16      u16x8  __attribute__((ext_vector_type(8)));
typedef u16      u16x4  __attribute__((ext_vector_type(4)));

#define BATCH 16
#define T0 64000
#define T1 32000
#define T2 16000
#define T3 8000
#define NT3 250          // t3 outputs per mega block; 32 blocks x 250 = 8000 exactly
#define NBLKX 32
#define NROWS1 1040      // local y1 rows staged (520 LDS lines)

static __device__ __forceinline__ u16 f2h(float f) {
    _Float16 h = (_Float16)f;
    u16 u;
    __builtin_memcpy(&u, &h, 2);
    return u;
}

// ---------------- weight prep (f16, transposed for coalesced A-frag reads) + cnt zero
// a2t[kk][g][o][j]: kk 0..8, g=0..3 (i-granule), o=0..63, j=0..7 (i=8g+j)   18432 u16
// a3t[kk][g][o][j]: kk 0..8, g=0..7,              o=0..127, j=0..7          73728 u16
__global__ __launch_bounds__(256) void prep_w_k(const float* __restrict__ w2,
                                                const float* __restrict__ w3,
                                                u16* __restrict__ a2t,
                                                u16* __restrict__ a3t,
                                                int* __restrict__ cnt) {
    int idx = blockIdx.x * 256 + threadIdx.x;
    if (idx < 18432) {
        int j = idx & 7, o = (idx >> 3) & 63, g = (idx >> 9) & 3, kk = idx >> 11;
        a2t[idx] = f2h(w2[(o * 32 + g * 8 + j) * 9 + kk]);
    } else if (idx < 18432 + 73728) {
        int jdx = idx - 18432;
        int j = jdx & 7, o = (jdx >> 3) & 127, g = (jdx >> 10) & 7, kk = jdx >> 13;
        a3t[jdx] = f2h(w3[(o * 64 + g * 8 + j) * 9 + kk]);
    } else if (idx < 18432 + 73728 + 16) {
        cnt[idx - 18432 - 73728] = 0;
    }
}

// ---------------- mega: conv1(scalar VALU) -> conv2(MFMA, in-place LDS)
//                  -> conv3(MFMA)+pool -> feats tail (last block per batch)
// Proven-component ledger (R1..R7):
//  - Phase A scalar conv1 (R1: 45.7us); interior blocks skip bounds checks, float2
//    loads (base even -> 8B aligned; bit-identical). R4 MFMA-conv1: worse. Dead end.
//  - Phase B: 2 chunks of 256 y2 rows at launch_bounds(512,2). Merged chunks (R2)
//    or tighter reg caps (R5) SPILL (signature: VGPR_Count drops, WRITE_SIZE jumps).
//  - Phase C: M=128 x N=256 (2x4 waves of 64x64), acc3[2][2].
//  - Epilogue: LDS reduce -> per-block PARTIAL SLOT (R8): R1->R4 A/B/A + R7 null
//    result isolated the +5.4us tail cost to the barrier-after-atomicAdd drain
//    (4096 RMWs/batch onto ~4 cache lines at the coherent point; every block's
//    __syncthreads waits vmcnt(0) behind that queue). Fix: each block writes its
//    own partials[b][blk][128] slot with agent-scope RELAXED stores (sc1
//    write-through, coalesced, no contention); tail block sums 32 slots with
//    agent-scope loads. NO per-store RELEASE (would emit per-store waitcnts).
//  - Tail: NO __threadfence() (R2/R3: buffer_wbl2 L2-writeback per block, ~55us).
//    sc1 stores complete at the coherent point; __syncthreads drains vmcnt(0), so
//    the cnt atomicAdd is ordered after them. Tail reads are agent-scope (immune
//    to non-coherent per-XCD L2).
//  - Tail feats matmul over all 512 threads with float4 wl loads (R7).
__global__ __launch_bounds__(512, 2) void mega_k(const float* __restrict__ audio,
                                                 const float* __restrict__ w1,
                                                 const float* __restrict__ b1,
                                                 const u16* __restrict__ a2t,
                                                 const float* __restrict__ b2,
                                                 const u16* __restrict__ a3t,
                                                 const float* __restrict__ b3,
                                                 float* __restrict__ partials,
                                                 int* __restrict__ cnt,
                                                 const float* __restrict__ wl,
                                                 const float* __restrict__ bl,
                                                 float* __restrict__ featbuf) {
    __shared__ u16 sm[520 * 64];           // 66,560 B -> 2 blocks/CU
    const int tid = threadIdx.x;
    const int b = blockIdx.y;
    const int r0 = blockIdx.x * NT3;
    const int lane = tid & 63, wv = tid >> 6;          // wv 0..7
    const int ls = lane >> 5, ln = lane & 31;

    // ---- Phase A: scalar conv1 into LDS (y1 rows 0..1039; global t1 = 4*r0-12+l1)
    {
        const float* ar = audio + (size_t)b * T0;
        const bool edge = (blockIdx.x == 0) || (blockIdx.x == NBLKX - 1);
        #pragma unroll
        for (int rep = 0; rep < 3; ++rep) {
            int l1 = rep * 512 + tid;
            if (l1 >= NROWS1) break;
            int t1 = 4 * r0 - 12 + l1;
            int rr = l1 >> 1, pp = l1 & 1;
            if (edge && (t1 < 0 || t1 >= T1)) {
                u16x8 z;
                #pragma unroll
                for (int q = 0; q < 8; ++q) z[q] = 0;
                #pragma unroll
                for (int g = 0; g < 4; ++g) {
                    int slot = (pp * 4 + g) ^ (rr & 7);
                    *(u16x8*)(sm + rr * 64 + slot * 8) = z;
                }
            } else {
                int base = 2 * t1 - 4;
                float x[9];
                if (edge) {
                    #pragma unroll
                    for (int k = 0; k < 9; ++k) {
                        int t0v = base + k;
                        x[k] = (t0v >= 0 && t0v < T0) ? ar[t0v] : 0.f;
                    }
                } else {
                    // base is even -> 8B-aligned float2 loads; bit-identical values
                    const float2* p2 = (const float2*)(ar + base);
                    #pragma unroll
                    for (int q = 0; q < 4; ++q) {
                        float2 c = p2[q];
                        x[2 * q]     = c.x;
                        x[2 * q + 1] = c.y;
                    }
                    x[8] = ar[base + 8];
                }
                #pragma unroll
                for (int g = 0; g < 4; ++g) {
                    u16x8 v;
                    #pragma unroll
                    for (int j = 0; j < 8; ++j) {
                        int ch = g * 8 + j;
                        float acc = b1[ch];
                        #pragma unroll
                        for (int k = 0; k < 9; ++k) acc = fmaf(x[k], w1[ch * 9 + k], acc);
                        v[j] = f2h(fmaxf(acc, 0.f));
                    }
                    int slot = (pp * 4 + g) ^ (rr & 7);
                    *(u16x8*)(sm + rr * 64 + slot * 8) = v;
                }
            }
        }
    }
    __syncthreads();

    // ---- Phase B: conv2 in 2 chunks of 256 y2 rows, in-place write-back
    for (int cc = 0; cc < 2; ++cc) {
        int nl = cc * 256 + 32 * wv + ln;   // this lane's y2 row (B column)
        f32x16 acc2[2];
        #pragma unroll
        for (int mi = 0; mi < 2; ++mi)
            #pragma unroll
            for (int q = 0; q < 16; ++q) acc2[mi][q] = 0.f;
        f16x8 bfB[2];
        #pragma unroll 3
        for (int kk = 0; kk < 9; ++kk) {
            {
                int rr = nl + (kk >> 1);
                int pp = kk & 1;
                #pragma unroll
                for (int step = 0; step < 2; ++step) {
                    int slot = (pp * 4 + 2 * step + ls) ^ (rr & 7);
                    bfB[step] = *(const f16x8*)(sm + rr * 64 + slot * 8);
                }
            }
            const u16* ap = a2t + kk * 2048;
            #pragma unroll
            for (int step = 0; step < 2; ++step) {
                f16x8 af0 = *(const f16x8*)(ap + (2 * step + ls) * 512 + ln * 8);
                f16x8 af1 = *(const f16x8*)(ap + (2 * step + ls) * 512 + (32 + ln) * 8);
                acc2[0] = __builtin_amdgcn_mfma_f32_32x32x16_f16(af0, bfB[step], acc2[0], 0, 0, 0);
                acc2[1] = __builtin_amdgcn_mfma_f32_32x32x16_f16(af1, bfB[step], acc2[1], 0, 0, 0);
            }
        }
        __syncthreads();                    // all chunk reads done before overwrite
        int l2 = nl;
        int t2 = 2 * r0 - 4 + l2;
        bool valid = (t2 >= 0) && (t2 < T2);
        #pragma unroll
        for (int mi = 0; mi < 2; ++mi)
            #pragma unroll
            for (int q = 0; q < 4; ++q) {
                u16x4 v;
                #pragma unroll
                for (int d = 0; d < 4; ++d) {
                    int o = 32 * mi + 8 * q + 4 * ls + d;
                    float xv = valid ? fmaxf(acc2[mi][4 * q + d] + b2[o], 0.f) : 0.f;
                    v[d] = f2h(xv);
                }
                int gy = 4 * mi + q;
                int sy = gy ^ ((l2 >> 1) & 7);
                *(u16x4*)(sm + l2 * 64 + sy * 8 + ls * 4) = v;
            }
        __syncthreads();
    }

    // ---- Phase C: conv3 MFMA + mean-pool (M=128 x N=256; 2x4 waves of 64x64)
    const int mh = wv & 1, nh = wv >> 1;               // mh 0..1, nh 0..3
    f32x16 acc3[2][2];
    #pragma unroll
    for (int mi = 0; mi < 2; ++mi)
        #pragma unroll
        for (int ni = 0; ni < 2; ++ni)
            #pragma unroll
            for (int q = 0; q < 16; ++q) acc3[mi][ni][q] = 0.f;

    f16x8 bf[2][4];
    #pragma unroll 3
    for (int kk = 0; kk < 9; ++kk) {
        const u16* ap = a3t + kk * 8192;
        {
            #pragma unroll
            for (int ni = 0; ni < 2; ++ni) {
                int nl = 64 * nh + 32 * ni + ln;
                int l2 = 2 * nl + kk;                  // <= 518 < 520
                int rrC = nl + (kk >> 1);
                #pragma unroll
                for (int step = 0; step < 4; ++step) {
                    int sy = (2 * step + ls) ^ (rrC & 7);
                    bf[ni][step] = *(const f16x8*)(sm + l2 * 64 + sy * 8);
                }
            }
        }
        #pragma unroll
        for (int step = 0; step < 4; ++step) {
            f16x8 af0 = *(const f16x8*)(ap + (2 * step + ls) * 1024 + (64 * mh + ln) * 8);
            f16x8 af1 = *(const f16x8*)(ap + (2 * step + ls) * 1024 + (64 * mh + 32 + ln) * 8);
            #pragma unroll
            for (int ni = 0; ni < 2; ++ni) {
                acc3[0][ni] = __builtin_amdgcn_mfma_f32_32x32x16_f16(af0, bf[ni][step], acc3[0][ni], 0, 0, 0);
                acc3[1][ni] = __builtin_amdgcn_mfma_f32_32x32x16_f16(af1, bf[ni][step], acc3[1][ni], 0, 0, 0);
            }
        }
    }

    // epilogue: bias+relu, mask nl>=250, per-wave partials -> LDS reduce -> slot store
    float loc[32];
    #pragma unroll
    for (int mi = 0; mi < 2; ++mi)
        #pragma unroll
        for (int r = 0; r < 16; ++r) {
            int o = 64 * mh + 32 * mi + (r & 3) + 8 * (r >> 2) + 4 * ls;
            float bias = b3[o];
            float s = 0.f;
            #pragma unroll
            for (int ni = 0; ni < 2; ++ni) {
                int nl = 64 * nh + 32 * ni + ln;
                float v = fmaxf(acc3[mi][ni][r] + bias, 0.f);
                s += (nl < NT3) ? v : 0.f;
            }
            loc[mi * 16 + r] = s;
        }
    __syncthreads();
    float* smf = (float*)sm;               // [4 nh][128 o][32 ln] = 64 KB <= 66,560 B
    #pragma unroll
    for (int mi = 0; mi < 2; ++mi)
        #pragma unroll
        for (int r = 0; r < 16; ++r) {
            int o = 64 * mh + 32 * mi + (r & 3) + 8 * (r >> 2) + 4 * ls;
            smf[nh * 4096 + o * 32 + ln] = loc[mi * 16 + r];
        }
    __syncthreads();
    if (tid < 128) {
        int o = tid;
        float s = 0.f;
        #pragma unroll
        for (int j = 0; j < 32; ++j) {
            int col = (j + o) & 31;
            s += smf[o * 32 + col] + smf[4096 + o * 32 + col]
               + smf[8192 + o * 32 + col] + smf[12288 + o * 32 + col];
        }
        // own slot, coalesced, agent scope (sc1 write-through) -> no RMW contention
        __hip_atomic_store(&partials[((size_t)b * NBLKX + blockIdx.x) * 128 + o], s,
                           __ATOMIC_RELAXED, __HIP_MEMORY_SCOPE_AGENT);
    }

    // ---- tail: last block of this batch computes feats (no fence; see header)
    __syncthreads();                        // drains vmcnt(0): slot stores complete
    int* smi = (int*)sm;
    if (tid == 0) {
        int done = atomicAdd(&cnt[b], 1);
        smi[0] = (done == NBLKX - 1) ? 1 : 0;
    }
    __syncthreads();
    if (smi[0]) {
        float* pr = (float*)sm + 64;        // [4][128] cross-slot partial staging
        {
            int o = tid & 127, sub = tid >> 7;     // sub 0..3
            const float* base = partials + (size_t)b * NBLKX * 128 + o;
            float s = 0.f;
            #pragma unroll
            for (int q = 0; q < 8; ++q)
                s += __hip_atomic_load(base + (sub + 4 * q) * 128,
                                       __ATOMIC_RELAXED, __HIP_MEMORY_SCOPE_AGENT);
            pr[sub * 128 + o] = s;
        }
        __syncthreads();
        float* pl = (float*)sm + 64 + 512;  // [128] pooled mean
        float* fl = (float*)sm + 64 + 512 + 128;   // [128] feat staging
        if (tid < 128)
            pl[tid] = (pr[tid] + pr[128 + tid] + pr[256 + tid] + pr[384 + tid])
                      * (1.0f / (float)T3);
        __syncthreads();
        {
            // feats matmul: all 512 threads; 4 threads per output o (i-split 32)
            int o = tid >> 2, sub = tid & 3;
            const float4* wp = (const float4*)(wl + o * 128 + sub * 32);
            const float4* pp4 = (const float4*)(pl + sub * 32);
            float s = 0.f;
            #pragma unroll
            for (int q = 0; q < 8; ++q) {
                float4 w4 = wp[q];
                float4 p4 = pp4[q];
                s += w4.x * p4.x + w4.y * p4.y + w4.z * p4.z + w4.w * p4.w;
            }
            s += __shfl_xor(s, 1);
            s += __shfl_xor(s, 2);
            if (sub == 0) fl[o] = s + bl[o];
        }
        __syncthreads();
        if (tid < 128) {
            float feat = fl[tid];
            if (tid < 64) {                 // wave 0: amps + normalize
                float r = fmaxf(feat, 0.f);
                float ssum = r;
                #pragma unroll
                for (int off = 32; off > 0; off >>= 1) ssum += __shfl_xor(ssum, off);
                featbuf[b * 128 + tid] = r / (ssum + 1e-6f);
            } else {                        // noise_mag raw
                featbuf[b * 128 + tid] = feat;
            }
        }
    }
}

// ---------------- synthesis: Chebyshev sin-recurrence, 4 samples/thread, float4 I/O
// sin(2*pi*(h+1)*u) = 2*cos(2*pi*u)*sin(2*pi*h*u) - sin(2*pi*(h-1)*u)
__global__ __launch_bounds__(256) void synth_k(const float* __restrict__ f0,
                                               const float* __restrict__ wn,
                                               const float* __restrict__ featbuf,
                                               float* __restrict__ out) {
    const int tid = threadIdx.x;
    const int b = blockIdx.y;
    __shared__ float sa[64];
    __shared__ float nm[64];
    if (tid < 64) sa[tid] = featbuf[b * 128 + tid];
    else if (tid < 128) nm[tid - 64] = featbuf[b * 128 + tid];
    __syncthreads();

    const int t0v = blockIdx.x * 1024 + tid * 4;
    if (t0v >= T0) return;                  // tail (after the barrier)

    const float4 fv = *(const float4*)(f0 + (size_t)b * T0 + t0v);
    const float4 wv = *(const float4*)(wn + (size_t)b * T0 + t0v);

    float sc[4], sp[4], tc[4], ac[4];
    #pragma unroll
    for (int s = 0; s < 4; ++s) {
        // u = f0 * t * 4/63999 (linspace incl endpoint); frac in double (phase can
        // reach ~1e5 revolutions), then recurrence runs entirely in fp32.
        double u = (double)((&fv.x)[s]) * ((double)(t0v + s) * (4.0 / 63999.0));
        float uf = (float)(u - floor(u));
        sc[s] = __builtin_amdgcn_sinf(uf);           // sin(2*pi*u)
        tc[s] = 2.0f * __builtin_amdgcn_cosf(uf);    // 2*cos(2*pi*u)
        sp[s] = 0.f;
        ac[s] = 0.f;
    }
    #pragma unroll
    for (int h = 0; h < 64; ++h) {
        float a = sa[h];
        #pragma unroll
        for (int s = 0; s < 4; ++s) {
            ac[s] = fmaf(a, sc[s], ac[s]);
            float sn = fmaf(tc[s], sc[s], -sp[s]);   // sin(2*pi*(h+2)*u)
            sp[s] = sc[s];
            sc[s] = sn;
        }
    }
    float4 o;
    #pragma unroll
    for (int s = 0; s < 4; ++s)
        (&o.x)[s] = ac[s] + (&wv.x)[s] * nm[(t0v + s) / 1000];
    *(float4*)(out + (size_t)b * T0 + t0v) = o;
}

extern "C" void kernel_launch(void* const* d_in, const int* in_sizes, int n_in,
                              void* d_out, int out_size, void* d_ws, size_t ws_size,
                              hipStream_t stream) {
    const float* audio = (const float*)d_in[0];
    const float* f0    = (const float*)d_in[1];
    const float* wn    = (const float*)d_in[2];
    const float* w1    = (const float*)d_in[3];
    const float* b1    = (const float*)d_in[4];
    const float* w2    = (const float*)d_in[5];
    const float* b2    = (const float*)d_in[6];
    const float* w3    = (const float*)d_in[7];
    const float* b3    = (const float*)d_in[8];
    const float* wl    = (const float*)d_in[9];
    const float* bl    = (const float*)d_in[10];
    float* out = (float*)d_out;

    char* ws = (char*)d_ws;
    int*   cnt      = (int*)(ws);                  // 16 int (zeroed by prep_w_k)
    float* featbuf  = (float*)(ws + 1024);         // 2048 f32 (written by mega tail)
    u16*   a2t      = (u16*)(ws + 16384);          // 18432 u16
    u16*   a3t      = (u16*)(ws + 16384 + 36864);  // 73728 u16
    float* partials = (float*)(ws + 16384 + 36864 + 147456);  // 512 x 128 f32 = 256 KB

    prep_w_k<<<361, 256, 0, stream>>>(w2, w3, a2t, a3t, cnt);
    mega_k<<<dim3(NBLKX, BATCH), 512, 0, stream>>>(audio, w1, b1, a2t, b2, a3t, b3,
                                                   partials, cnt, wl, bl, featbuf);
    synth_k<<<dim3((T0 + 1023) / 1024, BATCH), 256, 0, stream>>>(f0, wn, featbuf, out);
}

// Round 9
// 125.607 us; speedup vs baseline: 1.0463x; 1.0463x over previous
//
#include <hip/hip_runtime.h>
#include <hip/hip_bf16.h>
#include <math.h>

typedef unsigned short u16;
typedef _Float16 f16x8 __attribute__((ext_vector_type(8)));
typedef float    f32x16 __attribute__((ext_vector_type(16)));
typedef u16      u16x8  __attribute__((ext_vector_type(8)));
typedef u16      u16x4  __attribute__((ext_vector_type(4)));

#define BATCH 16
#define T0 64000
#define T1 32000
#define T2 16000
#define T3 8000
#define NT3 250          // t3 outputs per mega block; 32 blocks x 250 = 8000 exactly
#define NBLKX 32
#define NROWS1 1040      // local y1 rows staged (520 LDS lines)

static __device__ __forceinline__ u16 f2h(float f) {
    _Float16 h = (_Float16)f;
    u16 u;
    __builtin_memcpy(&u, &h, 2);
    return u;
}

// ---------------- weight prep (f16, transposed for coalesced A-frag reads) + cnt zero
// a2t[kk][g][o][j]: kk 0..8, g=0..3 (i-granule), o=0..63, j=0..7 (i=8g+j)   18432 u16
// a3t[kk][g][o][j]: kk 0..8, g=0..7,              o=0..127, j=0..7          73728 u16
__global__ __launch_bounds__(256) void prep_w_k(const float* __restrict__ w2,
                                                const float* __restrict__ w3,
                                                u16* __restrict__ a2t,
                                                u16* __restrict__ a3t,
                                                int* __restrict__ cnt) {
    int idx = blockIdx.x * 256 + threadIdx.x;
    if (idx < 18432) {
        int j = idx & 7, o = (idx >> 3) & 63, g = (idx >> 9) & 3, kk = idx >> 11;
        a2t[idx] = f2h(w2[(o * 32 + g * 8 + j) * 9 + kk]);
    } else if (idx < 18432 + 73728) {
        int jdx = idx - 18432;
        int j = jdx & 7, o = (jdx >> 3) & 127, g = (jdx >> 10) & 7, kk = jdx >> 13;
        a3t[jdx] = f2h(w3[(o * 64 + g * 8 + j) * 9 + kk]);
    } else if (idx < 18432 + 73728 + 16) {
        cnt[idx - 18432 - 73728] = 0;
    }
}

// ---------------- mega: conv1(scalar VALU) -> conv2(MFMA merged chunks, in-place LDS)
//                  -> conv3(MFMA)+pool -> feats tail (last block per batch)
// Proven-component ledger (R1..R8):
//  - Phase A scalar conv1; interior blocks skip bounds checks, float2 loads.
//    R4 MFMA-conv1: worse (+250K bank-conflict cycles). Dead end.
//  - Phase B MERGED chunks (R2, exonerated in R8 post-mortem): single kk loop,
//    A-frags loaded ONCE for both 256-row chunks (halves Phase B A-traffic:
//    1.15MB -> 576KB per CU through L1), barriers 4 -> 2. Register math:
//    acc2[2][2] = 64 AGPR + af 16 + bfB/addressing ~= 120 <= 128 at (512,2).
//    NOTE: trace VGPR_Count EXCLUDES AGPRs (R2 showed "56" and was misread as a
//    spill; R2's 103us was the fence, proven by R3's A/B). True spill signature =
//    WRITE_SIZE jumping to MBs of scratch (R5: 8.4MB).
//  - Phase C: M=128 x N=256 (2x4 waves of 64x64), acc3[2][2].
//  - Epilogue: LDS reduce -> per-block partial slot, agent-scope relaxed stores
//    (R8; equal to atomicAdd within-run, structurally cleaner).
//  - Tail: NO __threadfence() (R2/R3: buffer_wbl2 L2-writeback per block, ~55us).
//    sc1 stores complete at the coherent point; __syncthreads drains vmcnt(0), so
//    the cnt atomicAdd is ordered after them. Tail reads agent-scope.
//  - Cross-run caution: ~10% clock drift observed between sessions (identical
//    work counters, 45.7 vs 51us). Only within-run deltas are trustworthy.
__global__ __launch_bounds__(512, 2) void mega_k(const float* __restrict__ audio,
                                                 const float* __restrict__ w1,
                                                 const float* __restrict__ b1,
                                                 const u16* __restrict__ a2t,
                                                 const float* __restrict__ b2,
                                                 const u16* __restrict__ a3t,
                                                 const float* __restrict__ b3,
                                                 float* __restrict__ partials,
                                                 int* __restrict__ cnt,
                                                 const float* __restrict__ wl,
                                                 const float* __restrict__ bl,
                                                 float* __restrict__ featbuf) {
    __shared__ u16 sm[520 * 64];           // 66,560 B -> 2 blocks/CU
    const int tid = threadIdx.x;
    const int b = blockIdx.y;
    const int r0 = blockIdx.x * NT3;
    const int lane = tid & 63, wv = tid >> 6;          // wv 0..7
    const int ls = lane >> 5, ln = lane & 31;

    // ---- Phase A: scalar conv1 into LDS (y1 rows 0..1039; global t1 = 4*r0-12+l1)
    {
        const float* ar = audio + (size_t)b * T0;
        const bool edge = (blockIdx.x == 0) || (blockIdx.x == NBLKX - 1);
        #pragma unroll
        for (int rep = 0; rep < 3; ++rep) {
            int l1 = rep * 512 + tid;
            if (l1 >= NROWS1) break;
            int t1 = 4 * r0 - 12 + l1;
            int rr = l1 >> 1, pp = l1 & 1;
            if (edge && (t1 < 0 || t1 >= T1)) {
                u16x8 z;
                #pragma unroll
                for (int q = 0; q < 8; ++q) z[q] = 0;
                #pragma unroll
                for (int g = 0; g < 4; ++g) {
                    int slot = (pp * 4 + g) ^ (rr & 7);
                    *(u16x8*)(sm + rr * 64 + slot * 8) = z;
                }
            } else {
                int base = 2 * t1 - 4;
                float x[9];
                if (edge) {
                    #pragma unroll
                    for (int k = 0; k < 9; ++k) {
                        int t0v = base + k;
                        x[k] = (t0v >= 0 && t0v < T0) ? ar[t0v] : 0.f;
                    }
                } else {
                    // base is even -> 8B-aligned float2 loads; bit-identical values
                    const float2* p2 = (const float2*)(ar + base);
                    #pragma unroll
                    for (int q = 0; q < 4; ++q) {
                        float2 c = p2[q];
                        x[2 * q]     = c.x;
                        x[2 * q + 1] = c.y;
                    }
                    x[8] = ar[base + 8];
                }
                #pragma unroll
                for (int g = 0; g < 4; ++g) {
                    u16x8 v;
                    #pragma unroll
                    for (int j = 0; j < 8; ++j) {
                        int ch = g * 8 + j;
                        float acc = b1[ch];
                        #pragma unroll
                        for (int k = 0; k < 9; ++k) acc = fmaf(x[k], w1[ch * 9 + k], acc);
                        v[j] = f2h(fmaxf(acc, 0.f));
                    }
                    int slot = (pp * 4 + g) ^ (rr & 7);
                    *(u16x8*)(sm + rr * 64 + slot * 8) = v;
                }
            }
        }
    }
    __syncthreads();

    // ---- Phase B: conv2, both 256-row chunks in one kk loop (A-frags loaded once)
    {
        f32x16 acc2[2][2];                  // [cc][mi]
        #pragma unroll
        for (int cc = 0; cc < 2; ++cc)
            #pragma unroll
            for (int mi = 0; mi < 2; ++mi)
                #pragma unroll
                for (int q = 0; q < 16; ++q) acc2[cc][mi][q] = 0.f;
        #pragma unroll 3
        for (int kk = 0; kk < 9; ++kk) {
            const u16* ap = a2t + kk * 2048;
            f16x8 af[2][2];
            #pragma unroll
            for (int step = 0; step < 2; ++step) {
                af[step][0] = *(const f16x8*)(ap + (2 * step + ls) * 512 + ln * 8);
                af[step][1] = *(const f16x8*)(ap + (2 * step + ls) * 512 + (32 + ln) * 8);
            }
            int pp = kk & 1, kh = kk >> 1;
            #pragma unroll
            for (int cc = 0; cc < 2; ++cc) {
                int nl = cc * 256 + 32 * wv + ln;
                int rr = nl + kh;                     // <= 515 < 520
                #pragma unroll
                for (int step = 0; step < 2; ++step) {
                    int slot = (pp * 4 + 2 * step + ls) ^ (rr & 7);
                    f16x8 bfB = *(const f16x8*)(sm + rr * 64 + slot * 8);
                    acc2[cc][0] = __builtin_amdgcn_mfma_f32_32x32x16_f16(af[step][0], bfB, acc2[cc][0], 0, 0, 0);
                    acc2[cc][1] = __builtin_amdgcn_mfma_f32_32x32x16_f16(af[step][1], bfB, acc2[cc][1], 0, 0, 0);
                }
            }
        }
        __syncthreads();                    // ALL y1 reads done before overwrite
        #pragma unroll
        for (int cc = 0; cc < 2; ++cc) {
            int l2 = cc * 256 + 32 * wv + ln;
            int t2 = 2 * r0 - 4 + l2;
            bool valid = (t2 >= 0) && (t2 < T2);
            #pragma unroll
            for (int mi = 0; mi < 2; ++mi)
                #pragma unroll
                for (int q = 0; q < 4; ++q) {
                    u16x4 v;
                    #pragma unroll
                    for (int d = 0; d < 4; ++d) {
                        int o = 32 * mi + 8 * q + 4 * ls + d;
                        float xv = valid ? fmaxf(acc2[cc][mi][4 * q + d] + b2[o], 0.f) : 0.f;
                        v[d] = f2h(xv);
                    }
                    int gy = 4 * mi + q;
                    int sy = gy ^ ((l2 >> 1) & 7);
                    *(u16x4*)(sm + l2 * 64 + sy * 8 + ls * 4) = v;
                }
        }
        __syncthreads();
    }

    // ---- Phase C: conv3 MFMA + mean-pool (M=128 x N=256; 2x4 waves of 64x64)
    const int mh = wv & 1, nh = wv >> 1;               // mh 0..1, nh 0..3
    f32x16 acc3[2][2];
    #pragma unroll
    for (int mi = 0; mi < 2; ++mi)
        #pragma unroll
        for (int ni = 0; ni < 2; ++ni)
            #pragma unroll
            for (int q = 0; q < 16; ++q) acc3[mi][ni][q] = 0.f;

    f16x8 bf[2][4];
    #pragma unroll 3
    for (int kk = 0; kk < 9; ++kk) {
        const u16* ap = a3t + kk * 8192;
        {
            #pragma unroll
            for (int ni = 0; ni < 2; ++ni) {
                int nl = 64 * nh + 32 * ni + ln;
                int l2 = 2 * nl + kk;                  // <= 518 < 520
                int rrC = nl + (kk >> 1);
                #pragma unroll
                for (int step = 0; step < 4; ++step) {
                    int sy = (2 * step + ls) ^ (rrC & 7);
                    bf[ni][step] = *(const f16x8*)(sm + l2 * 64 + sy * 8);
                }
            }
        }
        #pragma unroll
        for (int step = 0; step < 4; ++step) {
            f16x8 af0 = *(const f16x8*)(ap + (2 * step + ls) * 1024 + (64 * mh + ln) * 8);
            f16x8 af1 = *(const f16x8*)(ap + (2 * step + ls) * 1024 + (64 * mh + 32 + ln) * 8);
            #pragma unroll
            for (int ni = 0; ni < 2; ++ni) {
                acc3[0][ni] = __builtin_amdgcn_mfma_f32_32x32x16_f16(af0, bf[ni][step], acc3[0][ni], 0, 0, 0);
                acc3[1][ni] = __builtin_amdgcn_mfma_f32_32x32x16_f16(af1, bf[ni][step], acc3[1][ni], 0, 0, 0);
            }
        }
    }

    // epilogue: bias+relu, mask nl>=250, per-wave partials -> LDS reduce -> slot store
    float loc[32];
    #pragma unroll
    for (int mi = 0; mi < 2; ++mi)
        #pragma unroll
        for (int r = 0; r < 16; ++r) {
            int o = 64 * mh + 32 * mi + (r & 3) + 8 * (r >> 2) + 4 * ls;
            float bias = b3[o];
            float s = 0.f;
            #pragma unroll
            for (int ni = 0; ni < 2; ++ni) {
                int nl = 64 * nh + 32 * ni + ln;
                float v = fmaxf(acc3[mi][ni][r] + bias, 0.f);
                s += (nl < NT3) ? v : 0.f;
            }
            loc[mi * 16 + r] = s;
        }
    __syncthreads();
    float* smf = (float*)sm;               // [4 nh][128 o][32 ln] = 64 KB <= 66,560 B
    #pragma unroll
    for (int mi = 0; mi < 2; ++mi)
        #pragma unroll
        for (int r = 0; r < 16; ++r) {
            int o = 64 * mh + 32 * mi + (r & 3) + 8 * (r >> 2) + 4 * ls;
            smf[nh * 4096 + o * 32 + ln] = loc[mi * 16 + r];
        }
    __syncthreads();
    if (tid < 128) {
        int o = tid;
        float s = 0.f;
        #pragma unroll
        for (int j = 0; j < 32; ++j) {
            int col = (j + o) & 31;
            s += smf[o * 32 + col] + smf[4096 + o * 32 + col]
               + smf[8192 + o * 32 + col] + smf[12288 + o * 32 + col];
        }
        // own slot, coalesced, agent scope (sc1 write-through) -> no RMW contention
        __hip_atomic_store(&partials[((size_t)b * NBLKX + blockIdx.x) * 128 + o], s,
                           __ATOMIC_RELAXED, __HIP_MEMORY_SCOPE_AGENT);
    }

    // ---- tail: last block of this batch computes feats (no fence; see header)
    __syncthreads();                        // drains vmcnt(0): slot stores complete
    int* smi = (int*)sm;
    if (tid == 0) {
        int done = atomicAdd(&cnt[b], 1);
        smi[0] = (done == NBLKX - 1) ? 1 : 0;
    }
    __syncthreads();
    if (smi[0]) {
        float* pr = (float*)sm + 64;        // [4][128] cross-slot partial staging
        {
            int o = tid & 127, sub = tid >> 7;     // sub 0..3
            const float* base = partials + (size_t)b * NBLKX * 128 + o;
            float s = 0.f;
            #pragma unroll
            for (int q = 0; q < 8; ++q)
                s += __hip_atomic_load(base + (sub + 4 * q) * 128,
                                       __ATOMIC_RELAXED, __HIP_MEMORY_SCOPE_AGENT);
            pr[sub * 128 + o] = s;
        }
        __syncthreads();
        float* pl = (float*)sm + 64 + 512;  // [128] pooled mean
        float* fl = (float*)sm + 64 + 512 + 128;   // [128] feat staging
        if (tid < 128)
            pl[tid] = (pr[tid] + pr[128 + tid] + pr[256 + tid] + pr[384 + tid])
                      * (1.0f / (float)T3);
        __syncthreads();
        {
            // feats matmul: all 512 threads; 4 threads per output o (i-split 32)
            int o = tid >> 2, sub = tid & 3;
            const float4* wp = (const float4*)(wl + o * 128 + sub * 32);
            const float4* pp4 = (const float4*)(pl + sub * 32);
            float s = 0.f;
            #pragma unroll
            for (int q = 0; q < 8; ++q) {
                float4 w4 = wp[q];
                float4 p4 = pp4[q];
                s += w4.x * p4.x + w4.y * p4.y + w4.z * p4.z + w4.w * p4.w;
            }
            s += __shfl_xor(s, 1);
            s += __shfl_xor(s, 2);
            if (sub == 0) fl[o] = s + bl[o];
        }
        __syncthreads();
        if (tid < 128) {
            float feat = fl[tid];
            if (tid < 64) {                 // wave 0: amps + normalize
                float r = fmaxf(feat, 0.f);
                float ssum = r;
                #pragma unroll
                for (int off = 32; off > 0; off >>= 1) ssum += __shfl_xor(ssum, off);
                featbuf[b * 128 + tid] = r / (ssum + 1e-6f);
            } else {                        // noise_mag raw
                featbuf[b * 128 + tid] = feat;
            }
        }
    }
}

// ---------------- synthesis: Chebyshev sin-recurrence, 4 samples/thread, float4 I/O
// sin(2*pi*(h+1)*u) = 2*cos(2*pi*u)*sin(2*pi*h*u) - sin(2*pi*(h-1)*u)
__global__ __launch_bounds__(256) void synth_k(const float* __restrict__ f0,
                                               const float* __restrict__ wn,
                                               const float* __restrict__ featbuf,
                                               float* __restrict__ out) {
    const int tid = threadIdx.x;
    const int b = blockIdx.y;
    __shared__ float sa[64];
    __shared__ float nm[64];
    if (tid < 64) sa[tid] = featbuf[b * 128 + tid];
    else if (tid < 128) nm[tid - 64] = featbuf[b * 128 + tid];
    __syncthreads();

    const int t0v = blockIdx.x * 1024 + tid * 4;
    if (t0v >= T0) return;                  // tail (after the barrier)

    const float4 fv = *(const float4*)(f0 + (size_t)b * T0 + t0v);
    const float4 wv = *(const float4*)(wn + (size_t)b * T0 + t0v);

    float sc[4], sp[4], tc[4], ac[4];
    #pragma unroll
    for (int s = 0; s < 4; ++s) {
        // u = f0 * t * 4/63999 (linspace incl endpoint); frac in double (phase can
        // reach ~1e5 revolutions), then recurrence runs entirely in fp32.
        double u = (double)((&fv.x)[s]) * ((double)(t0v + s) * (4.0 / 63999.0));
        float uf = (float)(u - floor(u));
        sc[s] = __builtin_amdgcn_sinf(uf);           // sin(2*pi*u)
        tc[s] = 2.0f * __builtin_amdgcn_cosf(uf);    // 2*cos(2*pi*u)
        sp[s] = 0.f;
        ac[s] = 0.f;
    }
    #pragma unroll
    for (int h = 0; h < 64; ++h) {
        float a = sa[h];
        #pragma unroll
        for (int s = 0; s < 4; ++s) {
            ac[s] = fmaf(a, sc[s], ac[s]);
            float sn = fmaf(tc[s], sc[s], -sp[s]);   // sin(2*pi*(h+2)*u)
            sp[s] = sc[s];
            sc[s] = sn;
        }
    }
    float4 o;
    #pragma unroll
    for (int s = 0; s < 4; ++s)
        (&o.x)[s] = ac[s] + (&wv.x)[s] * nm[(t0v + s) / 1000];
    *(float4*)(out + (size_t)b * T0 + t0v) = o;
}

extern "C" void kernel_launch(void* const* d_in, const int* in_sizes, int n_in,
                              void* d_out, int out_size, void* d_ws, size_t ws_size,
                              hipStream_t stream) {
    const float* audio = (const float*)d_in[0];
    const float* f0    = (const float*)d_in[1];
    const float* wn    = (const float*)d_in[2];
    const float* w1    = (const float*)d_in[3];
    const float* b1    = (const float*)d_in[4];
    const float* w2    = (const float*)d_in[5];
    const float* b2    = (const float*)d_in[6];
    const float* w3    = (const float*)d_in[7];
    const float* b3    = (const float*)d_in[8];
    const float* wl    = (const float*)d_in[9];
    const float* bl    = (const float*)d_in[10];
    float* out = (float*)d_out;

    char* ws = (char*)d_ws;
    int*   cnt      = (int*)(ws);                  // 16 int (zeroed by prep_w_k)
    float* featbuf  = (float*)(ws + 1024);         // 2048 f32 (written by mega tail)
    u16*   a2t      = (u16*)(ws + 16384);          // 18432 u16
    u16*   a3t      = (u16*)(ws + 16384 + 36864);  // 73728 u16
    float* partials = (float*)(ws + 16384 + 36864 + 147456);  // 512 x 128 f32 = 256 KB

    prep_w_k<<<361, 256, 0, stream>>>(w2, w3, a2t, a3t, cnt);
    mega_k<<<dim3(NBLKX, BATCH), 512, 0, stream>>>(audio, w1, b1, a2t, b2, a3t, b3,
                                                   partials, cnt, wl, bl, featbuf);
    synth_k<<<dim3((T0 + 1023) / 1024, BATCH), 256, 0, stream>>>(f0, wn, featbuf, out);
}